// Round 4
// baseline (317.955 us; speedup 1.0000x reference)
//
#include <hip/hip_runtime.h>
#include <hip/hip_bf16.h>

typedef unsigned short us16;
typedef __attribute__((ext_vector_type(8))) short short8;   // 8 bf16 in 4 VGPRs
typedef __attribute__((ext_vector_type(4))) float float4v;  // MFMA C/D 16x16
typedef __attribute__((ext_vector_type(16))) float float16v; // MFMA C/D 32x32
typedef __attribute__((ext_vector_type(4))) unsigned uintx4;

#define E_DIM 1024
#define S_LEN 2048
#define B_DIM 2
#define H_DIM 16
#define HD_DIM 64
#define M_ROWS 4096
#define SCALE2 0.18033688011112042f  // (1/8) * log2(e), folded into Wcq/bcq

__device__ __forceinline__ float b2f(us16 b) {
    return __uint_as_float(((unsigned int)b) << 16);
}
__device__ __forceinline__ us16 f2b(float f) {           // RNE
    unsigned int u = __float_as_uint(f);
    unsigned int r = (u + 0x7fffu + ((u >> 16) & 1u)) >> 16;
    return (us16)r;
}

// async global->LDS, 16B/lane; lds base wave-uniform (HW adds lane*16)
__device__ __forceinline__ void gload16(const us16* g, us16* lds_uniform_base) {
    __builtin_amdgcn_global_load_lds(
        (const __attribute__((address_space(1))) void*)g,
        (__attribute__((address_space(3))) void*)lds_uniform_base, 16, 0, 0);
}

// ---------------------------------------------------------------------------
// prep: ALL preprocessing in one dispatch (13873 blocks x 256 thr).
// ---------------------------------------------------------------------------
__global__ __launch_bounds__(256) void prep(
    const float* __restrict__ q, const float* __restrict__ k, const float* __restrict__ v,
    const float* __restrict__ Wq, const float* __restrict__ Wk, const float* __restrict__ Wv,
    const float* __restrict__ Whq, const float* __restrict__ Whk, const float* __restrict__ Whv,
    const float* __restrict__ Wo,
    const float* __restrict__ bq, const float* __restrict__ bk, const float* __restrict__ bv,
    const float* __restrict__ bhq, const float* __restrict__ bhk, const float* __restrict__ bhv,
    const int* __restrict__ mask,
    us16* qb, us16* kb, us16* vb, us16* Wqb, us16* Wkb, us16* Wvb,
    us16* WhqT, us16* WhkT, us16* WhvT, us16* WoT,
    us16* marr,
    float* bcq, float* bck, float* bcv, float* zbias)
{
    __shared__ us16 tile[32][33];
    __shared__ float red[4][64];
    int blk = blockIdx.x, tid = threadIdx.x;

    if (blk < 7680) {            // f32 -> bf16 streaming converts
        const float* in; us16* out; int idx;
        if (blk < 6144) {
            int z = blk >> 11, rem = blk & 2047;
            in = z == 0 ? q : z == 1 ? k : v;
            out = z == 0 ? qb : z == 1 ? kb : vb;
            idx = (rem * 256 + tid) * 8;
        } else {
            int t = blk - 6144, z = t >> 9, rem = t & 511;
            in = z == 0 ? Wq : z == 1 ? Wk : Wv;
            out = z == 0 ? Wqb : z == 1 ? Wkb : Wvb;
            idx = (rem * 256 + tid) * 8;
        }
        float4 f0 = *(const float4*)(in + idx);
        float4 f1 = *(const float4*)(in + idx + 4);
        us16 t8[8] = {f2b(f0.x), f2b(f0.y), f2b(f0.z), f2b(f0.w),
                      f2b(f1.x), f2b(f1.y), f2b(f1.z), f2b(f1.w)};
        *(uint4*)(out + idx) = *(const uint4*)t8;
    } else if (blk < 11776) {    // weight transposes
        int t = blk - 7680, z = t >> 10, rem = t & 1023;
        const float* in = z == 0 ? Whq : z == 1 ? Whk : z == 2 ? Whv : Wo;
        us16* out = z == 0 ? WhqT : z == 1 ? WhkT : z == 2 ? WhvT : WoT;
        int mode = (z < 3) ? 1 : 0;
        int bx = rem & 31, by = rem >> 5;
        int tx = tid & 31, ty = tid >> 5;
#pragma unroll
        for (int i = 0; i < 4; ++i) {
            int e = by * 32 + ty + i * 8;
            int c = bx * 32 + tx;
            size_t src;
            if (mode == 0) src = (size_t)e * E_DIM + c;
            else           src = ((size_t)(c >> 6) * E_DIM + e) * 64 + (c & 63);
            tile[ty + i * 8][tx] = f2b(in[src]);
        }
        __syncthreads();
#pragma unroll
        for (int i = 0; i < 4; ++i) {
            int c = bx * 32 + ty + i * 8;
            int e = by * 32 + tx;
            out[(size_t)c * E_DIM + e] = tile[tx][ty + i * 8];
        }
    } else if (blk < 13824) {    // mask -> additive bf16 bias, 32x32 C-lane order
        // record (b,kt,q0t,w): 2048 els = [tt:2][lane:64][el:16]
        // el e at lane: t_local = (e&3) + 8*(e>>2) + 4*(lane>>5) + tt*32
        int g = (blk - 11776) * 256 + tid;            // 0..524287
        int lane = g & 63, tt = (g >> 6) & 1, wv = (g >> 7) & 3;
        int q0t = (g >> 9) & 15, kt = (g >> 13) & 31, bb = (g >> 18) & 1;
        int half = lane >> 5;
        int qq = q0t * 128 + wv * 32 + (lane & 31);
        int tb = kt * 64 + tt * 32 + 4 * half;
        const int* mp = mask + ((size_t)bb * S_LEN + qq) * S_LEN + tb;
        const us16 NEGB = f2b(-1e38f);
        us16 t16[16];
#pragma unroll
        for (int gi = 0; gi < 4; ++gi) {
            int4 mv = *(const int4*)(mp + gi * 8);
            t16[gi * 4 + 0] = mv.x ? NEGB : (us16)0;
            t16[gi * 4 + 1] = mv.y ? NEGB : (us16)0;
            t16[gi * 4 + 2] = mv.z ? NEGB : (us16)0;
            t16[gi * 4 + 3] = mv.w ? NEGB : (us16)0;
        }
        *(uint4*)&marr[(size_t)g * 16]     = *(const uint4*)&t16[0];
        *(uint4*)&marr[(size_t)g * 16 + 8] = *(const uint4*)&t16[8];
    } else if (blk < 13872) {    // combined bias (Q-bias pre-scaled by SCALE2)
        int t = blk - 13824, z = t >> 4, h = t & 15;
        const float* bg = z == 0 ? bq : z == 1 ? bk : bv;
        const float* Wh = z == 0 ? Whq : z == 1 ? Whk : Whv;
        const float* bh = z == 0 ? bhq : z == 1 ? bhk : bhv;
        float* bc = z == 0 ? bcq : z == 1 ? bck : bcv;
        float sc = (z == 0) ? SCALE2 : 1.0f;
        int d = tid & 63, part = tid >> 6;
        float acc = 0.f;
        int j0 = part * 256;
        for (int j = j0; j < j0 + 256; ++j)
            acc += bg[j] * Wh[((size_t)h * E_DIM + j) * HD_DIM + d];
        red[part][d] = acc;
        __syncthreads();
        if (tid < 64)
            bc[h * 64 + tid] = (red[0][tid] + red[1][tid] + red[2][tid] + red[3][tid] + bh[h * 64 + tid]) * sc;
    } else {                     // zero zbias
        int i = (blk - 13872) * 256 + tid;
        if (i < 1024) zbias[i] = 0.f;
    }
}

// ---------------------------------------------------------------------------
// GEMM body, 128x128x32 tile (big batched projections).
// omode 1: bf16 [B,H,S,HD] (bias[col]); 3: bf16 [B,H,HD,S] (bias[row]).
// ---------------------------------------------------------------------------
#define BK 32

__device__ __forceinline__ void gemm_body(
    const us16* __restrict__ A, const us16* __restrict__ Bt,
    const float* __restrict__ bias, void* __restrict__ Cp,
    int M, int N, int K, int bxt, int byt, int omode)
{
    __shared__ us16 As[128 * BK];
    __shared__ us16 Bs[128 * BK];

    int tid = threadIdx.x;
    int wave = tid >> 6, lane = tid & 63;
    int quad = lane >> 4, l16 = lane & 15;
    int wm = (wave >> 1) * 64, wn = (wave & 1) * 64;
    int bm0 = byt * 128, bn0 = bxt * 128;
    int srow = lane >> 2;
    int gcol = (((lane & 3) ^ (srow & 3)) << 3);
    int rslot = ((quad ^ (l16 & 3)) << 3);

    float4v acc[4][4];
#pragma unroll
    for (int i = 0; i < 4; ++i)
#pragma unroll
        for (int j = 0; j < 4; ++j)
#pragma unroll
            for (int r = 0; r < 4; ++r) acc[i][j][r] = 0.f;

    for (int k0 = 0; k0 < K; k0 += BK) {
#pragma unroll
        for (int c = 0; c < 2; ++c) {
            int r0 = 32 * wave + 16 * c;
            gload16(A  + (size_t)(bm0 + r0 + srow) * K + k0 + gcol, &As[r0 * BK]);
            gload16(Bt + (size_t)(bn0 + r0 + srow) * K + k0 + gcol, &Bs[r0 * BK]);
        }
        __syncthreads();
        short8 af[4], bfr[4];
#pragma unroll
        for (int i = 0; i < 4; ++i)
            af[i] = *(const short8*)&As[(wm + i * 16 + l16) * BK + rslot];
#pragma unroll
        for (int j = 0; j < 4; ++j)
            bfr[j] = *(const short8*)&Bs[(wn + j * 16 + l16) * BK + rslot];
#pragma unroll
        for (int i = 0; i < 4; ++i)
#pragma unroll
            for (int j = 0; j < 4; ++j)
                acc[i][j] = __builtin_amdgcn_mfma_f32_16x16x32_bf16(af[i], bfr[j], acc[i][j], 0, 0, 0);
        __syncthreads();
    }

#pragma unroll
    for (int i = 0; i < 4; ++i) {
#pragma unroll
        for (int j = 0; j < 4; ++j) {
#pragma unroll
            for (int r = 0; r < 4; ++r) {
                int row = bm0 + wm + i * 16 + quad * 4 + r;
                int col = bn0 + wn + j * 16 + l16;
                float vv = acc[i][j][r] + ((omode == 3) ? bias[row] : bias[col]);
                if (omode == 1) {
                    int b = row >> 11, s = row & 2047, h = col >> 6, d = col & 63;
                    ((us16*)Cp)[(((size_t)(b * H_DIM + h) * S_LEN + s) * HD_DIM) + d] = f2b(vv);
                } else {  // 3: row=c (h*64+d), col=b*2048+s -> [B,H,HD,S]
                    int h = row >> 6, d = row & 63, b = col >> 11, sl = col & 2047;
                    ((us16*)Cp)[(((size_t)(b * H_DIM + h) * HD_DIM + d) * S_LEN) + sl] = f2b(vv);
                }
            }
        }
    }
}

// all three fused projections in ONE 768-block dispatch (3 blocks/CU)
__global__ __launch_bounds__(256) void proj_all(
    const us16* __restrict__ qb, const us16* __restrict__ kb, const us16* __restrict__ vb,
    const us16* __restrict__ WcqT, const us16* __restrict__ WckT, const us16* __restrict__ WcvT,
    const float* __restrict__ bcq, const float* __restrict__ bck, const float* __restrict__ bcv,
    us16* __restrict__ qhb, us16* __restrict__ khb, us16* __restrict__ vtb)
{
    int bx = blockIdx.x;
    int z = bx >> 8, t = bx & 255;
    if (z == 0)      gemm_body(qb, WcqT, bcq, qhb, M_ROWS, E_DIM, E_DIM, t & 7, t >> 3, 1);
    else if (z == 1) gemm_body(kb, WckT, bck, khb, M_ROWS, E_DIM, E_DIM, t & 7, t >> 3, 1);
    else             gemm_body(WcvT, vb, bcv, vtb, E_DIM, M_ROWS, E_DIM, t & 31, t >> 5, 3);
}

// ---------------------------------------------------------------------------
// 64x128-tile GEMM body. OMODE 0: bf16 [M,N]; 2: f32 [M,N]. bias[col], *oscale.
// ---------------------------------------------------------------------------
template<int OMODE>
__device__ __forceinline__ void gemm64_body(
    const us16* __restrict__ A, const us16* __restrict__ Bt,
    const float* __restrict__ bias, void* __restrict__ Cp,
    int M, int N, int K, int bxt, int byt, float oscale)
{
    __shared__ us16 As[64 * BK];
    __shared__ us16 Bs[128 * BK];

    int tid = threadIdx.x;
    int wave = tid >> 6, lane = tid & 63;
    int quad = lane >> 4, l16 = lane & 15;
    int wm = (wave >> 1) * 32, wn = (wave & 1) * 64;
    int bm0 = byt * 64, bn0 = bxt * 128;
    int srow = lane >> 2;
    int gcol = (((lane & 3) ^ (srow & 3)) << 3);
    int rslot = ((quad ^ (l16 & 3)) << 3);

    float4v acc[2][4];
#pragma unroll
    for (int i = 0; i < 2; ++i)
#pragma unroll
        for (int j = 0; j < 4; ++j)
#pragma unroll
            for (int r = 0; r < 4; ++r) acc[i][j][r] = 0.f;

    for (int k0 = 0; k0 < K; k0 += BK) {
        gload16(A + (size_t)(bm0 + 16 * wave + srow) * K + k0 + gcol, &As[16 * wave * BK]);
#pragma unroll
        for (int c = 0; c < 2; ++c) {
            int r0 = 32 * wave + 16 * c;
            gload16(Bt + (size_t)(bn0 + r0 + srow) * K + k0 + gcol, &Bs[r0 * BK]);
        }
        __syncthreads();
        short8 af[2], bfr[4];
#pragma unroll
        for (int i = 0; i < 2; ++i)
            af[i] = *(const short8*)&As[(wm + i * 16 + l16) * BK + rslot];
#pragma unroll
        for (int j = 0; j < 4; ++j)
            bfr[j] = *(const short8*)&Bs[(wn + j * 16 + l16) * BK + rslot];
#pragma unroll
        for (int i = 0; i < 2; ++i)
#pragma unroll
            for (int j = 0; j < 4; ++j)
                acc[i][j] = __builtin_amdgcn_mfma_f32_16x16x32_bf16(af[i], bfr[j], acc[i][j], 0, 0, 0);
        __syncthreads();
    }

#pragma unroll
    for (int i = 0; i < 2; ++i)
#pragma unroll
        for (int j = 0; j < 4; ++j)
#pragma unroll
            for (int r = 0; r < 4; ++r) {
                int row = bm0 + wm + i * 16 + quad * 4 + r;
                int col = bn0 + wn + j * 16 + l16;
                float vv = (acc[i][j][r] + bias[col]) * oscale;
                if (OMODE == 0) ((us16*)Cp)[(size_t)row * N + col] = f2b(vv);
                else            ((float*)Cp)[(size_t)row * N + col] = vv;
            }
}

// batched weight-combine: C_z = WhT_z @ Wb_z^T; z==0 output pre-scaled SCALE2
__global__ __launch_bounds__(256) void wgemm3(
    const us16* A0, const us16* A1, const us16* A2,
    const us16* B0, const us16* B1, const us16* B2,
    const float* zbias, us16* C0, us16* C1, us16* C2)
{
    int z = blockIdx.z;
    const us16* A = z == 0 ? A0 : z == 1 ? A1 : A2;
    const us16* Bt = z == 0 ? B0 : z == 1 ? B1 : B2;
    us16* C = z == 0 ? C0 : z == 1 ? C1 : C2;
    float sc = (z == 0) ? SCALE2 : 1.0f;
    gemm64_body<0>(A, Bt, zbias, C, E_DIM, E_DIM, E_DIM, blockIdx.x, blockIdx.y, sc);
}

// out projection: f32 out, grid (8,64)=512 blocks
__global__ __launch_bounds__(256) void gemm_out64(
    const us16* __restrict__ A, const us16* __restrict__ Bt,
    const float* __restrict__ bias, float* __restrict__ C, int M, int N, int K)
{
    gemm64_body<2>(A, Bt, bias, C, M, N, K, blockIdx.x, blockIdx.y, 1.0f);
}

// ---------------------------------------------------------------------------
// Flash attention, 32x32x16 MFMA, S^T formulation (fixed-max softmax; scores
// pre-scaled via Wcq). Mask = bf16 additive bias (marr) as MFMA C-init.
// P never touches LDS: cvt_pk_bf16 + v_permlane32_swap rebuild the PV
// A-fragments in registers (halves exchange t-slices). LDS traffic per MAC
// is half the 16x16 formulation. 4 waves x 32 qrows = Q-tile 128; K-tile 64;
// double-buffered K/V DMA, one raw barrier per tile; XCD-aware 1-D grid.
// ---------------------------------------------------------------------------
#define NT 16    // K-tiles per block (64 wide, 1024 kt per z-half)

__device__ __forceinline__ float16v mask16(uint4 a, uint4 b) {
    float16v m;
    unsigned ws[8] = {a.x, a.y, a.z, a.w, b.x, b.y, b.z, b.w};
#pragma unroll
    for (int j = 0; j < 8; ++j) {
        m[2 * j]     = __uint_as_float(ws[j] << 16);
        m[2 * j + 1] = __uint_as_float(ws[j] & 0xFFFF0000u);
    }
    return m;
}

// exp2 on 16 scores -> two bf16 A-fragments (t-windows lo/hi of this acc)
__device__ __forceinline__ void pfrag(const float16v s, float& lsum,
                                      short8& flo, short8& fhi) {
    float p[16];
#pragma unroll
    for (int r = 0; r < 16; ++r) p[r] = __builtin_amdgcn_exp2f(s[r]);
#pragma unroll
    for (int r = 0; r < 16; ++r) lsum += p[r];
    unsigned w0, w1, w2, w3, w4, w5, w6, w7;
    asm("v_cvt_pk_bf16_f32 %0, %1, %2" : "=v"(w0) : "v"(p[0]),  "v"(p[1]));
    asm("v_cvt_pk_bf16_f32 %0, %1, %2" : "=v"(w1) : "v"(p[2]),  "v"(p[3]));
    asm("v_cvt_pk_bf16_f32 %0, %1, %2" : "=v"(w2) : "v"(p[4]),  "v"(p[5]));
    asm("v_cvt_pk_bf16_f32 %0, %1, %2" : "=v"(w3) : "v"(p[6]),  "v"(p[7]));
    asm("v_cvt_pk_bf16_f32 %0, %1, %2" : "=v"(w4) : "v"(p[8]),  "v"(p[9]));
    asm("v_cvt_pk_bf16_f32 %0, %1, %2" : "=v"(w5) : "v"(p[10]), "v"(p[11]));
    asm("v_cvt_pk_bf16_f32 %0, %1, %2" : "=v"(w6) : "v"(p[12]), "v"(p[13]));
    asm("v_cvt_pk_bf16_f32 %0, %1, %2" : "=v"(w7) : "v"(p[14]), "v"(p[15]));
    // dst.hi <-> src.lo: gives both halves their missing t-slices
    asm("v_permlane32_swap_b32 %0, %1" : "+v"(w0), "+v"(w2));
    asm("v_permlane32_swap_b32 %0, %1" : "+v"(w1), "+v"(w3));
    asm("v_permlane32_swap_b32 %0, %1" : "+v"(w4), "+v"(w6));
    asm("v_permlane32_swap_b32 %0, %1" : "+v"(w5), "+v"(w7));
    uintx4 lo = {w0, w1, w2, w3}, hi = {w4, w5, w6, w7};
    flo = __builtin_bit_cast(short8, lo);
    fhi = __builtin_bit_cast(short8, hi);
}

__global__ __launch_bounds__(256) void attn_kernel(
    const us16* __restrict__ qh, const us16* __restrict__ kh,
    const us16* __restrict__ vt, const us16* __restrict__ marr,
    us16* __restrict__ o_p, float* __restrict__ l_p)
{
    __shared__ us16 Ks[2][64 * 64];   // [t][hd], chunk c at slot c^(t&7)
    __shared__ us16 Vs[2][64 * 64];   // V^T [d][t], chunk c at slot c^(d&7)

    int tid = threadIdx.x;
    int w = tid >> 6, lane = tid & 63;
    int q32 = lane & 31, half = lane >> 5;

    // XCD-aware decode: 4 heads per XCD so K/V panels stay L2-resident.
    int wg = blockIdx.x;                 // 0..1023
    int xcd = wg & 7, idx = wg >> 3;
    int bh = xcd * 4 + (idx >> 5);
    int rem = idx & 31;
    int z = rem >> 4;
    int q0t = rem & 15;
    int q0 = q0t * 128;
    int b = bh >> 4;
    const size_t base = (size_t)bh * (S_LEN * HD_DIM);

    // Q B-fragments: lane holds Q[hd = win*16 + half*8 + e][q = q32]
    int qrow = q0 + w * 32 + q32;
    short8 qf[4];
#pragma unroll
    for (int win = 0; win < 4; ++win)
        qf[win] = *(const short8*)(qh + base + (size_t)qrow * HD_DIM + win * 16 + half * 8);

    // staging: wave w stages 16 rows (2 gloads of 8 rows each) per buffer
    int strow = w * 16 + (lane >> 3);
    int scol = ((lane & 7) ^ (strow & 7)) * 8;
    const us16* ksrc0 = kh + base + (size_t)(z * 1024 + strow) * HD_DIM + scol;
    const us16* vsrc0 = vt + base + (size_t)strow * S_LEN + scol + z * 1024;

    // mask record (b,kt,q0t,w): [tt:2][lane:64][el:16]
    const us16* mrec = marr + ((((size_t)(b * 32 + z * 16) * 16 + q0t) * 4 + w) * 2048)
                            + (size_t)lane * 16;

    float16v oc0, oc1;
#pragma unroll
    for (int r = 0; r < 16; ++r) { oc0[r] = 0.f; oc1[r] = 0.f; }
    float lsum = 0.f;

    // prologue: stage tile 0, load tile-0 mask bias
    gload16(ksrc0,              &Ks[0][(w * 16) * 64]);
    gload16(ksrc0 + 8 * HD_DIM, &Ks[0][(w * 16 + 8) * 64]);
    gload16(vsrc0,              &Vs[0][(w * 16) * 64]);
    gload16(vsrc0 + 8 * S_LEN,  &Vs[0][(w * 16 + 8) * 64]);
    uint4 mc0 = *(const uint4*)(mrec);
    uint4 mc1 = *(const uint4*)(mrec + 8);
    uint4 mc2 = *(const uint4*)(mrec + 1024);
    uint4 mc3 = *(const uint4*)(mrec + 1032);
    asm volatile("s_waitcnt vmcnt(0)" ::: "memory");
    __builtin_amdgcn_s_barrier();
    __builtin_amdgcn_sched_barrier(0);

    for (int t = 0; t < NT; ++t) {
        int cur = t & 1;
        const us16* KsC = Ks[cur];
        const us16* VsC = Vs[cur];

        // issue next tile's DMA + mask loads early (hide under compute)
        uint4 mn0 = mc0, mn1 = mc1, mn2 = mc2, mn3 = mc3;
        if (t + 1 < NT) {
            const us16* kn = ksrc0 + (size_t)((t + 1) * 64) * HD_DIM;
            const us16* vn = vsrc0 + (t + 1) * 64;
            us16* kd = &Ks[cur ^ 1][(w * 16) * 64];
            us16* vd = &Vs[cur ^ 1][(w * 16) * 64];
            gload16(kn,              kd);
            gload16(kn + 8 * HD_DIM, kd + 8 * 64);
            gload16(vn,              vd);
            gload16(vn + 8 * S_LEN,  vd + 8 * 64);
            const us16* mp = mrec + (size_t)(t + 1) * 131072;
            mn0 = *(const uint4*)(mp);
            mn1 = *(const uint4*)(mp + 8);
            mn2 = *(const uint4*)(mp + 1024);
            mn3 = *(const uint4*)(mp + 1032);
        }

        // S^T = K·Q^T (two 32-row t-tiles), mask bias as C-init
        float16v s0 = mask16(mc0, mc1);
        float16v s1 = mask16(mc2, mc3);
        __builtin_amdgcn_s_setprio(1);
#pragma unroll
        for (int win = 0; win < 4; ++win) {
            int sl = ((win * 2 + half) ^ (lane & 7)) * 8;
            short8 kf0 = *(const short8*)&KsC[q32 * 64 + sl];
            short8 kf1 = *(const short8*)&KsC[(32 + q32) * 64 + sl];
            s0 = __builtin_amdgcn_mfma_f32_32x32x16_bf16(kf0, qf[win], s0, 0, 0, 0);
            s1 = __builtin_amdgcn_mfma_f32_32x32x16_bf16(kf1, qf[win], s1, 0, 0, 0);
        }
        __builtin_amdgcn_s_setprio(0);

        // softmax + in-register P A-fragments (4 t-windows of 16)
        short8 pf0, pf1, pf2, pf3;
        pfrag(s0, lsum, pf0, pf1);
        pfrag(s1, lsum, pf2, pf3);

        // PV: O[q][d] += P^T·V, d-tiles 0-31 / 32-63
        __builtin_amdgcn_s_setprio(1);
        {
            int sl0 = ((0 * 2 + half) ^ (lane & 7)) * 8;
            int sl1 = ((1 * 2 + half) ^ (lane & 7)) * 8;
            int sl2 = ((2 * 2 + half) ^ (lane & 7)) * 8;
            int sl3 = ((3 * 2 + half) ^ (lane & 7)) * 8;
            short8 vf;
            vf = *(const short8*)&VsC[q32 * 64 + sl0];
            oc0 = __builtin_amdgcn_mfma_f32_32x32x16_bf16(pf0, vf, oc0, 0, 0, 0);
            vf = *(const short8*)&VsC[(32 + q32) * 64 + sl0];
            oc1 = __builtin_amdgcn_mfma_f32_32x32x16_bf16(pf0, vf, oc1, 0, 0, 0);
            vf = *(const short8*)&VsC[q32 * 64 + sl1];
            oc0 = __builtin_amdgcn_mfma_f32_32x32x16_bf16(pf1, vf, oc0, 0, 0, 0);
            vf = *(const short8*)&VsC[(32 + q32) * 64 + sl1];
            oc1 = __builtin_amdgcn_mfma_f32_32x32x16_bf16(pf1, vf, oc1, 0, 0, 0);
            vf = *(const short8*)&VsC[q32 * 64 + sl2];
            oc0 = __builtin_amdgcn_mfma_f32_32x32x16_bf16(pf2, vf, oc0, 0, 0, 0);
            vf = *(const short8*)&VsC[(32 + q32) * 64 + sl2];
            oc1 = __builtin_amdgcn_mfma_f32_32x32x16_bf16(pf2, vf, oc1, 0, 0, 0);
            vf = *(const short8*)&VsC[q32 * 64 + sl3];
            oc0 = __builtin_amdgcn_mfma_f32_32x32x16_bf16(pf3, vf, oc0, 0, 0, 0);
            vf = *(const short8*)&VsC[(32 + q32) * 64 + sl3];
            oc1 = __builtin_amdgcn_mfma_f32_32x32x16_bf16(pf3, vf, oc1, 0, 0, 0);
        }
        __builtin_amdgcn_s_setprio(0);

        mc0 = mn0; mc1 = mn1; mc2 = mn2; mc3 = mn3;
        asm volatile("s_waitcnt vmcnt(0)" ::: "memory");
        __builtin_amdgcn_s_barrier();
        __builtin_amdgcn_sched_barrier(0);
    }

    // l[q]: halves hold complementary t-slices
    lsum += __shfl_xor(lsum, 32, 64);
    if (lane < 32)
        l_p[(size_t)z * 65536 + bh * S_LEN + q0 + w * 32 + lane] = lsum;

    // store partial O (undivided): lane col d = dtile*32 + q32, rows via reg
    int rowb = bh * S_LEN + q0 + w * 32;
#pragma unroll
    for (int r = 0; r < 16; ++r) {
        int qq = (r & 3) + 8 * (r >> 2) + 4 * half;
        size_t ro = (size_t)z * 4194304 + (size_t)(rowb + qq) * 64;
        o_p[ro + q32]      = f2b(oc0[r]);
        o_p[ro + 32 + q32] = f2b(oc1[r]);
    }
}

// combine: x[b,s,h*64+d] = (o0+o1)/(l0+l1); 2048 blocks x 256 thr, 8 els/thr
__global__ __launch_bounds__(256) void attn_combine(
    const us16* __restrict__ o_p, const float* __restrict__ l_p,
    us16* __restrict__ x)
{
    int fidx = blockIdx.x * 256 + threadIdx.x;       // 0..524287
    int rix = fidx >> 3;                             // row (bh*2048+s)
    int d8 = (fidx & 7) * 8;
    float linv = 1.0f / (l_p[rix] + l_p[65536 + rix]);
    uint4 a = *(const uint4*)(o_p + (size_t)rix * 64 + d8);
    uint4 c = *(const uint4*)(o_p + 4194304 + (size_t)rix * 64 + d8);
    const us16* ap = (const us16*)&a;
    const us16* cp = (const us16*)&c;
    us16 t8[8];
#pragma unroll
    for (int i = 0; i < 8; ++i)
        t8[i] = f2b((b2f(ap[i]) + b2f(cp[i])) * linv);
    int bh = rix >> 11, b = bh >> 4, h = bh & 15, s = rix & 2047;
    *(uint4*)&x[(size_t)(b * S_LEN + s) * E_DIM + h * HD_DIM + d8] = *(const uint4*)t8;
}

// ---------------------------------------------------------------------------
extern "C" void kernel_launch(void* const* d_in, const int* in_sizes, int n_in,
                              void* d_out, int out_size, void* d_ws, size_t ws_size,
                              hipStream_t stream) {
    const float* q    = (const float*)d_in[0];
    const float* k    = (const float*)d_in[1];
    const float* v    = (const float*)d_in[2];
    const int*   mask = (const int*)d_in[3];
    const float* Wq = (const float*)d_in[4];   const float* bq = (const float*)d_in[5];
    const float* Wk = (const float*)d_in[6];   const float* bk = (const float*)d_in[7];
    const float* Wv = (const float*)d_in[8];   const float* bv = (const float*)d_in[9];
    const float* Whq = (const float*)d_in[10]; const float* bhq = (const float*)d_in[11];
    const float* Whk = (const float*)d_in[12]; const float* bhk = (const float*)d_in[13];
    const float* Whv = (const float*)d_in[14]; const float* bhv = (const float*)d_in[15];
    const float* Wo = (const float*)d_in[16];  const float* bo = (const float*)d_in[17];

    us16* ws = (us16*)d_ws;
    const size_t M1 = (size_t)1 << 20;  // 1M bf16 elems = 2 MiB
    us16* WhqT = ws + 0 * M1;
    us16* WhkT = ws + 1 * M1;
    us16* WhvT = ws + 2 * M1;
    us16* WoT  = ws + 3 * M1;
    us16* WcqT = ws + 4 * M1;
    us16* WckT = ws + 5 * M1;
    us16* WcvT = ws + 6 * M1;
    us16* Wqb  = ws + 7 * M1;
    us16* Wkb  = ws + 8 * M1;
    us16* Wvb  = ws + 9 * M1;
    us16* qb   = ws + 10 * M1;   // 4M els each; o_p aliases qb..kb after proj
    us16* kb   = ws + 14 * M1;
    us16* vb   = ws + 18 * M1;
    us16* qhb  = ws + 22 * M1;   // [B,H,S,HD]
    us16* khb  = ws + 26 * M1;
    us16* vtb  = ws + 30 * M1;   // [B,H,HD,S]
    us16* o_p  = qb;             // 8M els (2 z-halves), qb/kb dead after proj
    us16* xb   = vb;             // vb dead after proj_all
    float* bcq   = (float*)(ws + 34 * M1);
    float* bck   = bcq + 1024;
    float* bcv   = bck + 1024;
    float* zbias = bcv + 1024;
    float* l_p   = (float*)(ws + 34 * M1 + 8192);        // 131072 f32 = 0.5 MiB
    us16*  marr  = ws + 35 * M1;                         // 8M els = 16 MiB

    prep<<<13873, 256, 0, stream>>>(q, k, v, Wq, Wk, Wv, Whq, Whk, Whv, Wo,
                                    bq, bk, bv, bhq, bhk, bhv, mask,
                                    qb, kb, vb, Wqb, Wkb, Wvb,
                                    WhqT, WhkT, WhvT, WoT, marr,
                                    bcq, bck, bcv, zbias);

    // combined weights WcT[c][e] = sum_j Wh[h][j][d]*W[e][j] (Q pre-scaled)
    wgemm3<<<dim3(8, 16, 3), 256, 0, stream>>>(WhqT, WhkT, WhvT, Wqb, Wkb, Wvb, zbias,
                                               WcqT, WckT, WcvT);

    // all three projections in one 768-block dispatch
    proj_all<<<768, 256, 0, stream>>>(qb, kb, vb, WcqT, WckT, WcvT,
                                      bcq, bck, bcv, qhb, khb, vtb);

    // K-split flash attention (partials, XCD-aware 1-D grid) + combine
    attn_kernel<<<1024, 256, 0, stream>>>(qhb, khb, vtb, marr, o_p, l_p);
    attn_combine<<<2048, 256, 0, stream>>>(o_p, l_p, xb);

    // output projection, f32 out
    gemm_out64<<<dim3(8, 64), 256, 0, stream>>>(xb, WoT, bo, (float*)d_out,
                                                M_ROWS, E_DIM, E_DIM);
}

// Round 5
// 304.602 us; speedup vs baseline: 1.0438x; 1.0438x over previous
//
#include <hip/hip_runtime.h>
#include <hip/hip_bf16.h>

typedef unsigned short us16;
typedef __attribute__((ext_vector_type(8))) short short8;   // 8 bf16 in 4 VGPRs
typedef __attribute__((ext_vector_type(4))) float float4v;  // MFMA C/D

#define E_DIM 1024
#define S_LEN 2048
#define B_DIM 2
#define H_DIM 16
#define HD_DIM 64
#define M_ROWS 4096
#define SCALE2 0.18033688011112042f  // (1/8) * log2(e), folded into Wcq/bcq

__device__ __forceinline__ float b2f(us16 b) {
    return __uint_as_float(((unsigned int)b) << 16);
}
__device__ __forceinline__ us16 f2b(float f) {           // RNE
    unsigned int u = __float_as_uint(f);
    unsigned int r = (u + 0x7fffu + ((u >> 16) & 1u)) >> 16;
    return (us16)r;
}

// async global->LDS, 16B/lane; lds base wave-uniform (HW adds lane*16)
__device__ __forceinline__ void gload16(const us16* g, us16* lds_uniform_base) {
    __builtin_amdgcn_global_load_lds(
        (const __attribute__((address_space(1))) void*)g,
        (__attribute__((address_space(3))) void*)lds_uniform_base, 16, 0, 0);
}

// ---------------------------------------------------------------------------
// prep: ALL preprocessing in one dispatch (15924 blocks x 256 thr).
// ---------------------------------------------------------------------------
__global__ __launch_bounds__(256) void prep(
    const float* __restrict__ q, const float* __restrict__ k, const float* __restrict__ v,
    const float* __restrict__ Wq, const float* __restrict__ Wk, const float* __restrict__ Wv,
    const float* __restrict__ Whq, const float* __restrict__ Whk, const float* __restrict__ Whv,
    const float* __restrict__ Wo,
    const float* __restrict__ bq, const float* __restrict__ bk, const float* __restrict__ bv,
    const float* __restrict__ bhq, const float* __restrict__ bhk, const float* __restrict__ bhv,
    const int* __restrict__ mask,
    us16* qb, us16* kb, us16* vb, us16* Wqb, us16* Wkb, us16* Wvb,
    us16* WhqT, us16* WhkT, us16* WhvT, us16* WoT,
    us16* marr,
    float* bcq, float* bck, float* bcv, float* zbias)
{
    __shared__ us16 tile[32][33];
    __shared__ float red[4][64];
    int blk = blockIdx.x, tid = threadIdx.x;

    if (blk < 7680) {            // f32 -> bf16 streaming converts
        const float* in; us16* out; int idx;
        if (blk < 6144) {
            int z = blk >> 11, rem = blk & 2047;
            in = z == 0 ? q : z == 1 ? k : v;
            out = z == 0 ? qb : z == 1 ? kb : vb;
            idx = (rem * 256 + tid) * 8;
        } else {
            int t = blk - 6144, z = t >> 9, rem = t & 511;
            in = z == 0 ? Wq : z == 1 ? Wk : Wv;
            out = z == 0 ? Wqb : z == 1 ? Wkb : Wvb;
            idx = (rem * 256 + tid) * 8;
        }
        float4 f0 = *(const float4*)(in + idx);
        float4 f1 = *(const float4*)(in + idx + 4);
        us16 t8[8] = {f2b(f0.x), f2b(f0.y), f2b(f0.z), f2b(f0.w),
                      f2b(f1.x), f2b(f1.y), f2b(f1.z), f2b(f1.w)};
        *(uint4*)(out + idx) = *(const uint4*)t8;
    } else if (blk < 11776) {    // weight transposes
        int t = blk - 7680, z = t >> 10, rem = t & 1023;
        const float* in = z == 0 ? Whq : z == 1 ? Whk : z == 2 ? Whv : Wo;
        us16* out = z == 0 ? WhqT : z == 1 ? WhkT : z == 2 ? WhvT : WoT;
        int mode = (z < 3) ? 1 : 0;
        int bx = rem & 31, by = rem >> 5;
        int tx = tid & 31, ty = tid >> 5;
#pragma unroll
        for (int i = 0; i < 4; ++i) {
            int e = by * 32 + ty + i * 8;
            int c = bx * 32 + tx;
            size_t src;
            if (mode == 0) src = (size_t)e * E_DIM + c;
            else           src = ((size_t)(c >> 6) * E_DIM + e) * 64 + (c & 63);
            tile[ty + i * 8][tx] = f2b(in[src]);
        }
        __syncthreads();
#pragma unroll
        for (int i = 0; i < 4; ++i) {
            int c = bx * 32 + ty + i * 8;
            int e = by * 32 + tx;
            out[(size_t)c * E_DIM + e] = tile[tx][ty + i * 8];
        }
    } else if (blk < 15872) {    // mask -> additive-bias bf16, attn lane order
        // layout [b][ktz:32][q0t:16][w:8][ld:2][lane:64][el:8]
        int g = (blk - 11776) * 256 + tid;            // 0..1048575
        int lane = g & 63, ld = (g >> 6) & 1, wv = (g >> 7) & 7;
        int q0t = (g >> 10) & 15, ktz = (g >> 14) & 31, bb = g >> 19;
        int quad = lane >> 4, l16 = lane & 15;
        int qq = q0t * 128 + wv * 16 + l16;
        int t0 = ktz * 64 + ld * 32 + quad * 4;
        const int* mp = mask + ((size_t)bb * S_LEN + qq) * S_LEN + t0;
        int4 ma = *(const int4*)mp;
        int4 mb2 = *(const int4*)(mp + 16);
        const us16 NEGB = f2b(-1e38f);
        us16 t8[8];
        t8[0] = ma.x ? NEGB : (us16)0;  t8[1] = ma.y ? NEGB : (us16)0;
        t8[2] = ma.z ? NEGB : (us16)0;  t8[3] = ma.w ? NEGB : (us16)0;
        t8[4] = mb2.x ? NEGB : (us16)0; t8[5] = mb2.y ? NEGB : (us16)0;
        t8[6] = mb2.z ? NEGB : (us16)0; t8[7] = mb2.w ? NEGB : (us16)0;
        *(uint4*)&marr[(size_t)g * 8] = *(const uint4*)t8;
    } else if (blk < 15920) {    // combined bias (Q-bias pre-scaled by SCALE2)
        int t = blk - 15872, z = t >> 4, h = t & 15;
        const float* bg = z == 0 ? bq : z == 1 ? bk : bv;
        const float* Wh = z == 0 ? Whq : z == 1 ? Whk : Whv;
        const float* bh = z == 0 ? bhq : z == 1 ? bhk : bhv;
        float* bc = z == 0 ? bcq : z == 1 ? bck : bcv;
        float sc = (z == 0) ? SCALE2 : 1.0f;
        int d = tid & 63, part = tid >> 6;
        float acc = 0.f;
        int j0 = part * 256;
        for (int j = j0; j < j0 + 256; ++j)
            acc += bg[j] * Wh[((size_t)h * E_DIM + j) * HD_DIM + d];
        red[part][d] = acc;
        __syncthreads();
        if (tid < 64)
            bc[h * 64 + tid] = (red[0][tid] + red[1][tid] + red[2][tid] + red[3][tid] + bh[h * 64 + tid]) * sc;
    } else {                     // zero zbias
        int i = (blk - 15920) * 256 + tid;
        if (i < 1024) zbias[i] = 0.f;
    }
}

// ---------------------------------------------------------------------------
// GEMM body, 128x128x32 tile (big batched projections).
// omode 1: bf16 [B,H,S,HD] (bias[col]); 3: bf16 [B,H,HD,S] (bias[row]).
// ---------------------------------------------------------------------------
#define BK 32

__device__ __forceinline__ void gemm_body(
    const us16* __restrict__ A, const us16* __restrict__ Bt,
    const float* __restrict__ bias, void* __restrict__ Cp,
    int M, int N, int K, int bxt, int byt, int omode)
{
    __shared__ us16 As[128 * BK];
    __shared__ us16 Bs[128 * BK];

    int tid = threadIdx.x;
    int wave = tid >> 6, lane = tid & 63;
    int quad = lane >> 4, l16 = lane & 15;
    int wm = (wave >> 1) * 64, wn = (wave & 1) * 64;
    int bm0 = byt * 128, bn0 = bxt * 128;
    int srow = lane >> 2;
    int gcol = (((lane & 3) ^ (srow & 3)) << 3);
    int rslot = ((quad ^ (l16 & 3)) << 3);

    float4v acc[4][4];
#pragma unroll
    for (int i = 0; i < 4; ++i)
#pragma unroll
        for (int j = 0; j < 4; ++j)
#pragma unroll
            for (int r = 0; r < 4; ++r) acc[i][j][r] = 0.f;

    for (int k0 = 0; k0 < K; k0 += BK) {
#pragma unroll
        for (int c = 0; c < 2; ++c) {
            int r0 = 32 * wave + 16 * c;
            gload16(A  + (size_t)(bm0 + r0 + srow) * K + k0 + gcol, &As[r0 * BK]);
            gload16(Bt + (size_t)(bn0 + r0 + srow) * K + k0 + gcol, &Bs[r0 * BK]);
        }
        __syncthreads();
        short8 af[4], bfr[4];
#pragma unroll
        for (int i = 0; i < 4; ++i)
            af[i] = *(const short8*)&As[(wm + i * 16 + l16) * BK + rslot];
#pragma unroll
        for (int j = 0; j < 4; ++j)
            bfr[j] = *(const short8*)&Bs[(wn + j * 16 + l16) * BK + rslot];
#pragma unroll
        for (int i = 0; i < 4; ++i)
#pragma unroll
            for (int j = 0; j < 4; ++j)
                acc[i][j] = __builtin_amdgcn_mfma_f32_16x16x32_bf16(af[i], bfr[j], acc[i][j], 0, 0, 0);
        __syncthreads();
    }

#pragma unroll
    for (int i = 0; i < 4; ++i) {
#pragma unroll
        for (int j = 0; j < 4; ++j) {
#pragma unroll
            for (int r = 0; r < 4; ++r) {
                int row = bm0 + wm + i * 16 + quad * 4 + r;
                int col = bn0 + wn + j * 16 + l16;
                float vv = acc[i][j][r] + ((omode == 3) ? bias[row] : bias[col]);
                if (omode == 1) {
                    int b = row >> 11, s = row & 2047, h = col >> 6, d = col & 63;
                    ((us16*)Cp)[(((size_t)(b * H_DIM + h) * S_LEN + s) * HD_DIM) + d] = f2b(vv);
                } else {  // 3: row=c (h*64+d), col=b*2048+s -> [B,H,HD,S]
                    int h = row >> 6, d = row & 63, b = col >> 11, sl = col & 2047;
                    ((us16*)Cp)[(((size_t)(b * H_DIM + h) * HD_DIM + d) * S_LEN) + sl] = f2b(vv);
                }
            }
        }
    }
}

// all three fused projections in ONE 768-block dispatch (3 blocks/CU)
__global__ __launch_bounds__(256) void proj_all(
    const us16* __restrict__ qb, const us16* __restrict__ kb, const us16* __restrict__ vb,
    const us16* __restrict__ WcqT, const us16* __restrict__ WckT, const us16* __restrict__ WcvT,
    const float* __restrict__ bcq, const float* __restrict__ bck, const float* __restrict__ bcv,
    us16* __restrict__ qhb, us16* __restrict__ khb, us16* __restrict__ vtb)
{
    int bx = blockIdx.x;
    int z = bx >> 8, t = bx & 255;
    if (z == 0)      gemm_body(qb, WcqT, bcq, qhb, M_ROWS, E_DIM, E_DIM, t & 7, t >> 3, 1);
    else if (z == 1) gemm_body(kb, WckT, bck, khb, M_ROWS, E_DIM, E_DIM, t & 7, t >> 3, 1);
    else             gemm_body(WcvT, vb, bcv, vtb, E_DIM, M_ROWS, E_DIM, t & 31, t >> 5, 3);
}

// ---------------------------------------------------------------------------
// 64x128-tile GEMM body. OMODE 0: bf16 [M,N]; 2: f32 [M,N]. bias[col], *oscale.
// ---------------------------------------------------------------------------
template<int OMODE>
__device__ __forceinline__ void gemm64_body(
    const us16* __restrict__ A, const us16* __restrict__ Bt,
    const float* __restrict__ bias, void* __restrict__ Cp,
    int M, int N, int K, int bxt, int byt, float oscale)
{
    __shared__ us16 As[64 * BK];
    __shared__ us16 Bs[128 * BK];

    int tid = threadIdx.x;
    int wave = tid >> 6, lane = tid & 63;
    int quad = lane >> 4, l16 = lane & 15;
    int wm = (wave >> 1) * 32, wn = (wave & 1) * 64;
    int bm0 = byt * 64, bn0 = bxt * 128;
    int srow = lane >> 2;
    int gcol = (((lane & 3) ^ (srow & 3)) << 3);
    int rslot = ((quad ^ (l16 & 3)) << 3);

    float4v acc[2][4];
#pragma unroll
    for (int i = 0; i < 2; ++i)
#pragma unroll
        for (int j = 0; j < 4; ++j)
#pragma unroll
            for (int r = 0; r < 4; ++r) acc[i][j][r] = 0.f;

    for (int k0 = 0; k0 < K; k0 += BK) {
        gload16(A + (size_t)(bm0 + 16 * wave + srow) * K + k0 + gcol, &As[16 * wave * BK]);
#pragma unroll
        for (int c = 0; c < 2; ++c) {
            int r0 = 32 * wave + 16 * c;
            gload16(Bt + (size_t)(bn0 + r0 + srow) * K + k0 + gcol, &Bs[r0 * BK]);
        }
        __syncthreads();
        short8 af[2], bfr[4];
#pragma unroll
        for (int i = 0; i < 2; ++i)
            af[i] = *(const short8*)&As[(wm + i * 16 + l16) * BK + rslot];
#pragma unroll
        for (int j = 0; j < 4; ++j)
            bfr[j] = *(const short8*)&Bs[(wn + j * 16 + l16) * BK + rslot];
#pragma unroll
        for (int i = 0; i < 2; ++i)
#pragma unroll
            for (int j = 0; j < 4; ++j)
                acc[i][j] = __builtin_amdgcn_mfma_f32_16x16x32_bf16(af[i], bfr[j], acc[i][j], 0, 0, 0);
        __syncthreads();
    }

#pragma unroll
    for (int i = 0; i < 2; ++i)
#pragma unroll
        for (int j = 0; j < 4; ++j)
#pragma unroll
            for (int r = 0; r < 4; ++r) {
                int row = bm0 + wm + i * 16 + quad * 4 + r;
                int col = bn0 + wn + j * 16 + l16;
                float vv = (acc[i][j][r] + bias[col]) * oscale;
                if (OMODE == 0) ((us16*)Cp)[(size_t)row * N + col] = f2b(vv);
                else            ((float*)Cp)[(size_t)row * N + col] = vv;
            }
}

// batched weight-combine: C_z = WhT_z @ Wb_z^T; z==0 output pre-scaled SCALE2
__global__ __launch_bounds__(256) void wgemm3(
    const us16* A0, const us16* A1, const us16* A2,
    const us16* B0, const us16* B1, const us16* B2,
    const float* zbias, us16* C0, us16* C1, us16* C2)
{
    int z = blockIdx.z;
    const us16* A = z == 0 ? A0 : z == 1 ? A1 : A2;
    const us16* Bt = z == 0 ? B0 : z == 1 ? B1 : B2;
    us16* C = z == 0 ? C0 : z == 1 ? C1 : C2;
    float sc = (z == 0) ? SCALE2 : 1.0f;
    gemm64_body<0>(A, Bt, zbias, C, E_DIM, E_DIM, E_DIM, blockIdx.x, blockIdx.y, sc);
}

// out projection: f32 out, grid (8,64)=512 blocks
__global__ __launch_bounds__(256) void gemm_out64(
    const us16* __restrict__ A, const us16* __restrict__ Bt,
    const float* __restrict__ bias, float* __restrict__ C, int M, int N, int K)
{
    gemm64_body<2>(A, Bt, bias, C, M, N, K, blockIdx.x, blockIdx.y, 1.0f);
}

// ---------------------------------------------------------------------------
// Flash attention, S^T formulation (fixed-max softmax; scores pre-scaled via
// Wcq). Mask = bf16 additive bias (marr) as MFMA C-init; P via cvt_pk; l via
// ones-MFMA. Depth-2 pipeline with COUNTED vmcnt (T3/T4): per tile
//   SM(t) -> PV(t) -> barrier -> issue DMA(t+2) -> vmcnt(2) -> barrier
//   -> QK(t+1)
// vmcnt(2) waits exactly for DMA(t+1) while DMA(t+2) stays in flight across
// the barrier -- each DMA gets a full extra tile of compute to hide under.
// XCD-aware 1-D grid (4 heads/XCD). 512 thr = 8 waves, Q-tile 128, K-split 2.
// ---------------------------------------------------------------------------
#define PST 72   // Pw row stride (els)
#define NT 16    // K-tiles per block (64 wide, 1024 kt per z-half)

__global__ __launch_bounds__(512) void attn_kernel(
    const us16* __restrict__ qh, const us16* __restrict__ kh,
    const us16* __restrict__ vt, const us16* __restrict__ marr,
    us16* __restrict__ o_p, float* __restrict__ l_p)
{
    __shared__ us16 Ks[2][64 * 64];   // packed, swizzled: slot c holds chunk c^(t&7)
    __shared__ us16 Vs[2][64 * 64];
    __shared__ us16 Pw[8][16 * PST];

    int tid = threadIdx.x;
    int w = tid >> 6, lane = tid & 63;
    int quad = lane >> 4, l16 = lane & 15;

    // XCD-aware decode: 4 heads per XCD so K/V panels stay L2-resident.
    int wg = blockIdx.x;                 // 0..1023
    int xcd = wg & 7, idx = wg >> 3;
    int bh = xcd * 4 + (idx >> 5);
    int rem = idx & 31;
    int z = rem >> 4;
    int q0t = rem & 15;
    int q0 = q0t * 128;
    int b = bh >> 4;
    const size_t base = (size_t)bh * (S_LEN * HD_DIM);

    int qrow = q0 + w * 16 + l16;
    short8 qf0, qf1;
    {
        const us16* qp = qh + base + (size_t)qrow * HD_DIM + quad * 8;
        qf0 = *(const short8*)qp;
        qf1 = *(const short8*)(qp + 32);
    }

    // ones B-fragment for l = P x 1 (all bf16 1.0)
    short8 onesf;
#pragma unroll
    for (int j = 0; j < 8; ++j) onesf[j] = (short)0x3F80;

    // staging geometry: wave w stages rows w*8..w*8+7; slot c <- chunk c^(row&7)
    int strow = w * 8 + (lane >> 3);
    int scol = ((lane & 7) ^ (strow & 7)) * 8;
    const us16* ksrc0 = kh + base + ((size_t)(z * 1024 + strow)) * HD_DIM + scol;
    const us16* vsrc0 = vt + base + (size_t)strow * S_LEN + scol + z * 1024;

    // mask-bias base: [b][ktz:32][q0t:16][w:8][ld:2][lane:64][el:8]
    const us16* mb0p = marr + ((((size_t)(b * 32 + z * 16) * 16 + q0t) * 8 + w) * 1024)
                            + (size_t)lane * 8;

    // frag-read slots
    int slotA = (quad ^ (l16 & 7)) * 8;     // chunk quad
    int slotB = slotA ^ 32;                 // chunk quad+4

    float4v o[4];
#pragma unroll
    for (int dt = 0; dt < 4; ++dt)
#pragma unroll
        for (int r = 0; r < 4; ++r) o[dt][r] = 0.f;
    float4v o_l;
#pragma unroll
    for (int r = 0; r < 4; ++r) o_l[r] = 0.f;

    // QK for tile in KsC with mask C-init (m0,m1) -> sc[4]
    auto QK = [&](const us16* KsC, uint4 m0, uint4 m1, float4v* sc) {
        __builtin_amdgcn_s_setprio(1);
#pragma unroll
        for (int ct = 0; ct < 4; ++ct) {
            int tt = ct * 16 + l16;
            short8 kf0 = *(const short8*)&KsC[tt * 64 + slotA];
            short8 kf1 = *(const short8*)&KsC[tt * 64 + slotB];
            unsigned w0, w1;
            if (ct == 0)      { w0 = m0.x; w1 = m0.y; }
            else if (ct == 1) { w0 = m0.z; w1 = m0.w; }
            else if (ct == 2) { w0 = m1.x; w1 = m1.y; }
            else              { w0 = m1.z; w1 = m1.w; }
            float4v a;
            a[0] = __uint_as_float(w0 << 16);
            a[1] = __uint_as_float(w0 & 0xFFFF0000u);
            a[2] = __uint_as_float(w1 << 16);
            a[3] = __uint_as_float(w1 & 0xFFFF0000u);
            a = __builtin_amdgcn_mfma_f32_16x16x32_bf16(kf0, qf0, a, 0, 0, 0);
            a = __builtin_amdgcn_mfma_f32_16x16x32_bf16(kf1, qf1, a, 0, 0, 0);
            sc[ct] = a;
        }
        __builtin_amdgcn_s_setprio(0);
    };

    // prologue: stage tiles 0 and 1; mask(0); wait tile 0 only; QK(0)
    gload16(ksrc0, &Ks[0][w * 512]);
    gload16(vsrc0, &Vs[0][w * 512]);
    gload16(ksrc0 + (size_t)64 * HD_DIM, &Ks[1][w * 512]);
    gload16(vsrc0 + 64, &Vs[1][w * 512]);
    uint4 mc0 = *(const uint4*)(mb0p);
    uint4 mc1 = *(const uint4*)(mb0p + 512);
    asm volatile("s_waitcnt vmcnt(2)" ::: "memory");
    __builtin_amdgcn_s_barrier();
    __builtin_amdgcn_sched_barrier(0);

    float4v sc[4];
    QK(Ks[0], mc0, mc1, sc);

    for (int t = 0; t < NT; ++t) {
        int cur = t & 1;

        // mask(t+1) load early (hides under SM+PV)
        uint4 mn0 = mc0, mn1 = mc1;
        if (t + 1 < NT) {
            const us16* mp = mb0p + (size_t)(t + 1) * 131072;
            mn0 = *(const uint4*)(mp);
            mn1 = *(const uint4*)(mp + 512);
        }

        // SM(t): exp2 + cvt_pk pack + b64 write (scores pre-scaled via Wcq)
#pragma unroll
        for (int ct = 0; ct < 4; ++ct) {
            float p0 = __builtin_amdgcn_exp2f(sc[ct][0]);
            float p1 = __builtin_amdgcn_exp2f(sc[ct][1]);
            float p2 = __builtin_amdgcn_exp2f(sc[ct][2]);
            float p3 = __builtin_amdgcn_exp2f(sc[ct][3]);
            uint2 pk;
            asm("v_cvt_pk_bf16_f32 %0, %1, %2" : "=v"(pk.x) : "v"(p0), "v"(p1));
            asm("v_cvt_pk_bf16_f32 %0, %1, %2" : "=v"(pk.y) : "v"(p2), "v"(p3));
            *(uint2*)&Pw[w][l16 * PST + ct * 16 + quad * 4] = pk;
        }

        // PV(t): O += P.V ; l += P.1 (ones-MFMA)
        short8 pf0 = *(const short8*)&Pw[w][l16 * PST + quad * 8];
        short8 pf1 = *(const short8*)&Pw[w][l16 * PST + 32 + quad * 8];
        const us16* VsC = Vs[cur];
        __builtin_amdgcn_s_setprio(1);
#pragma unroll
        for (int dt = 0; dt < 4; ++dt) {
            int d = dt * 16 + l16;
            short8 vf0 = *(const short8*)&VsC[d * 64 + slotA];
            short8 vf1 = *(const short8*)&VsC[d * 64 + slotB];
            o[dt] = __builtin_amdgcn_mfma_f32_16x16x32_bf16(pf0, vf0, o[dt], 0, 0, 0);
            o[dt] = __builtin_amdgcn_mfma_f32_16x16x32_bf16(pf1, vf1, o[dt], 0, 0, 0);
        }
        o_l = __builtin_amdgcn_mfma_f32_16x16x32_bf16(pf0, onesf, o_l, 0, 0, 0);
        o_l = __builtin_amdgcn_mfma_f32_16x16x32_bf16(pf1, onesf, o_l, 0, 0, 0);
        __builtin_amdgcn_s_setprio(0);

        if (t + 1 == NT) break;

        // all waves done reading buf[cur] -> safe to overwrite
        __builtin_amdgcn_s_barrier();
        __builtin_amdgcn_sched_barrier(0);

        if (t + 2 < NT) {
            gload16(ksrc0 + (size_t)((t + 2) * 64) * HD_DIM, &Ks[cur][w * 512]);
            gload16(vsrc0 + (t + 2) * 64, &Vs[cur][w * 512]);
            // outstanding: DMA(t+1)=2 + DMA(t+2)=2; wait until only t+2 remains
            asm volatile("s_waitcnt vmcnt(2)" ::: "memory");
        } else {
            // nothing more to issue; drain DMA(t+1)
            asm volatile("s_waitcnt vmcnt(0)" ::: "memory");
        }
        __builtin_amdgcn_s_barrier();
        __builtin_amdgcn_sched_barrier(0);

        // QK(t+1) from the freshly-ready buffer
        mc0 = mn0; mc1 = mn1;
        QK(Ks[cur ^ 1], mc0, mc1, sc);
    }

    // l: o_l holds row-sums for q = w*16 + quad*4 + r (all l16 cols equal)
    if (l16 == 0) {
#pragma unroll
        for (int r = 0; r < 4; ++r)
            l_p[(size_t)z * 65536 + bh * S_LEN + q0 + w * 16 + quad * 4 + r] = o_l[r];
    }

    // store partial O (undivided); rows quad*4+r, col d = dt*16+l16
    int rowg = bh * S_LEN + q0 + w * 16 + quad * 4;
#pragma unroll
    for (int dt = 0; dt < 4; ++dt)
#pragma unroll
        for (int r = 0; r < 4; ++r)
            o_p[(size_t)z * 4194304 + (size_t)(rowg + r) * 64 + dt * 16 + l16] = f2b(o[dt][r]);
}

// combine: x[b,s,h*64+d] = (o0+o1)/(l0+l1); 2048 blocks x 256 thr, 8 els/thr
__global__ __launch_bounds__(256) void attn_combine(
    const us16* __restrict__ o_p, const float* __restrict__ l_p,
    us16* __restrict__ x)
{
    int fidx = blockIdx.x * 256 + threadIdx.x;       // 0..524287
    int rix = fidx >> 3;                             // row (bh*2048+s)
    int d8 = (fidx & 7) * 8;
    float linv = 1.0f / (l_p[rix] + l_p[65536 + rix]);
    uint4 a = *(const uint4*)(o_p + (size_t)rix * 64 + d8);
    uint4 c = *(const uint4*)(o_p + 4194304 + (size_t)rix * 64 + d8);
    const us16* ap = (const us16*)&a;
    const us16* cp = (const us16*)&c;
    us16 t8[8];
#pragma unroll
    for (int i = 0; i < 8; ++i)
        t8[i] = f2b((b2f(ap[i]) + b2f(cp[i])) * linv);
    int bh = rix >> 11, b = bh >> 4, h = bh & 15, s = rix & 2047;
    *(uint4*)&x[(size_t)(b * S_LEN + s) * E_DIM + h * HD_DIM + d8] = *(const uint4*)t8;
}

// ---------------------------------------------------------------------------
extern "C" void kernel_launch(void* const* d_in, const int* in_sizes, int n_in,
                              void* d_out, int out_size, void* d_ws, size_t ws_size,
                              hipStream_t stream) {
    const float* q    = (const float*)d_in[0];
    const float* k    = (const float*)d_in[1];
    const float* v    = (const float*)d_in[2];
    const int*   mask = (const int*)d_in[3];
    const float* Wq = (const float*)d_in[4];   const float* bq = (const float*)d_in[5];
    const float* Wk = (const float*)d_in[6];   const float* bk = (const float*)d_in[7];
    const float* Wv = (const float*)d_in[8];   const float* bv = (const float*)d_in[9];
    const float* Whq = (const float*)d_in[10]; const float* bhq = (const float*)d_in[11];
    const float* Whk = (const float*)d_in[12]; const float* bhk = (const float*)d_in[13];
    const float* Whv = (const float*)d_in[14]; const float* bhv = (const float*)d_in[15];
    const float* Wo = (const float*)d_in[16];  const float* bo = (const float*)d_in[17];

    us16* ws = (us16*)d_ws;
    const size_t M1 = (size_t)1 << 20;  // 1M bf16 elems = 2 MiB
    us16* WhqT = ws + 0 * M1;
    us16* WhkT = ws + 1 * M1;
    us16* WhvT = ws + 2 * M1;
    us16* WoT  = ws + 3 * M1;
    us16* WcqT = ws + 4 * M1;
    us16* WckT = ws + 5 * M1;
    us16* WcvT = ws + 6 * M1;
    us16* Wqb  = ws + 7 * M1;
    us16* Wkb  = ws + 8 * M1;
    us16* Wvb  = ws + 9 * M1;
    us16* qb   = ws + 10 * M1;   // 4M els each; o_p aliases qb..kb after proj
    us16* kb   = ws + 14 * M1;
    us16* vb   = ws + 18 * M1;
    us16* qhb  = ws + 22 * M1;   // [B,H,S,HD]
    us16* khb  = ws + 26 * M1;
    us16* vtb  = ws + 30 * M1;   // [B,H,HD,S]
    us16* o_p  = qb;             // 8M els (2 z-halves), qb/kb dead after proj
    us16* xb   = vb;             // vb dead after proj_all
    float* bcq   = (float*)(ws + 34 * M1);
    float* bck   = bcq + 1024;
    float* bcv   = bck + 1024;
    float* zbias = bcv + 1024;
    float* l_p   = (float*)(ws + 34 * M1 + 8192);        // 131072 f32 = 0.5 MiB
    us16*  marr  = ws + 35 * M1;                         // 8M els = 16 MiB

    prep<<<15924, 256, 0, stream>>>(q, k, v, Wq, Wk, Wv, Whq, Whk, Whv, Wo,
                                    bq, bk, bv, bhq, bhk, bhv, mask,
                                    qb, kb, vb, Wqb, Wkb, Wvb,
                                    WhqT, WhkT, WhvT, WoT, marr,
                                    bcq, bck, bcv, zbias);

    // combined weights WcT[c][e] = sum_j Wh[h][j][d]*W[e][j] (Q pre-scaled)
    wgemm3<<<dim3(8, 16, 3), 256, 0, stream>>>(WhqT, WhkT, WhvT, Wqb, Wkb, Wvb, zbias,
                                               WcqT, WckT, WcvT);

    // all three projections in one 768-block dispatch
    proj_all<<<768, 256, 0, stream>>>(qb, kb, vb, WcqT, WckT, WcvT,
                                      bcq, bck, bcv, qhb, khb, vtb);

    // K-split flash attention (partials, XCD-aware 1-D grid) + combine
    attn_kernel<<<1024, 512, 0, stream>>>(qhb, khb, vtb, marr, o_p, l_p);
    attn_combine<<<2048, 256, 0, stream>>>(o_p, l_p, xb);

    // output projection, f32 out
    gemm_out64<<<dim3(8, 64), 256, 0, stream>>>(xb, WoT, bo, (float*)d_out,
                                                M_ROWS, E_DIM, E_DIM);
}

// Round 6
// 298.303 us; speedup vs baseline: 1.0659x; 1.0211x over previous
//
#include <hip/hip_runtime.h>
#include <hip/hip_bf16.h>

typedef unsigned short us16;
typedef __attribute__((ext_vector_type(8))) short short8;   // 8 bf16 in 4 VGPRs
typedef __attribute__((ext_vector_type(4))) float float4v;  // MFMA C/D

#define E_DIM 1024
#define S_LEN 2048
#define B_DIM 2
#define H_DIM 16
#define HD_DIM 64
#define M_ROWS 4096
#define SCALE2 0.18033688011112042f  // (1/8) * log2(e), folded into Wcq/bcq

__device__ __forceinline__ float b2f(us16 b) {
    return __uint_as_float(((unsigned int)b) << 16);
}
__device__ __forceinline__ us16 f2b(float f) {           // RNE
    unsigned int u = __float_as_uint(f);
    unsigned int r = (u + 0x7fffu + ((u >> 16) & 1u)) >> 16;
    return (us16)r;
}

// async global->LDS, 16B/lane; lds base wave-uniform (HW adds lane*16)
__device__ __forceinline__ void gload16(const us16* g, us16* lds_uniform_base) {
    __builtin_amdgcn_global_load_lds(
        (const __attribute__((address_space(1))) void*)g,
        (__attribute__((address_space(3))) void*)lds_uniform_base, 16, 0, 0);
}

// ---------------------------------------------------------------------------
// prep: ALL preprocessing in one dispatch (15924 blocks x 256 thr).
// ---------------------------------------------------------------------------
__global__ __launch_bounds__(256) void prep(
    const float* __restrict__ q, const float* __restrict__ k, const float* __restrict__ v,
    const float* __restrict__ Wq, const float* __restrict__ Wk, const float* __restrict__ Wv,
    const float* __restrict__ Whq, const float* __restrict__ Whk, const float* __restrict__ Whv,
    const float* __restrict__ Wo,
    const float* __restrict__ bq, const float* __restrict__ bk, const float* __restrict__ bv,
    const float* __restrict__ bhq, const float* __restrict__ bhk, const float* __restrict__ bhv,
    const int* __restrict__ mask,
    us16* qb, us16* kb, us16* vb, us16* Wqb, us16* Wkb, us16* Wvb,
    us16* WhqT, us16* WhkT, us16* WhvT, us16* WoT,
    us16* marr,
    float* bcq, float* bck, float* bcv, float* zbias)
{
    __shared__ us16 tile[32][33];
    __shared__ float red[4][64];
    int blk = blockIdx.x, tid = threadIdx.x;

    if (blk < 7680) {            // f32 -> bf16 streaming converts
        const float* in; us16* out; int idx;
        if (blk < 6144) {
            int z = blk >> 11, rem = blk & 2047;
            in = z == 0 ? q : z == 1 ? k : v;
            out = z == 0 ? qb : z == 1 ? kb : vb;
            idx = (rem * 256 + tid) * 8;
        } else {
            int t = blk - 6144, z = t >> 9, rem = t & 511;
            in = z == 0 ? Wq : z == 1 ? Wk : Wv;
            out = z == 0 ? Wqb : z == 1 ? Wkb : Wvb;
            idx = (rem * 256 + tid) * 8;
        }
        float4 f0 = *(const float4*)(in + idx);
        float4 f1 = *(const float4*)(in + idx + 4);
        us16 t8[8] = {f2b(f0.x), f2b(f0.y), f2b(f0.z), f2b(f0.w),
                      f2b(f1.x), f2b(f1.y), f2b(f1.z), f2b(f1.w)};
        *(uint4*)(out + idx) = *(const uint4*)t8;
    } else if (blk < 11776) {    // weight transposes
        int t = blk - 7680, z = t >> 10, rem = t & 1023;
        const float* in = z == 0 ? Whq : z == 1 ? Whk : z == 2 ? Whv : Wo;
        us16* out = z == 0 ? WhqT : z == 1 ? WhkT : z == 2 ? WhvT : WoT;
        int mode = (z < 3) ? 1 : 0;
        int bx = rem & 31, by = rem >> 5;
        int tx = tid & 31, ty = tid >> 5;
#pragma unroll
        for (int i = 0; i < 4; ++i) {
            int e = by * 32 + ty + i * 8;
            int c = bx * 32 + tx;
            size_t src;
            if (mode == 0) src = (size_t)e * E_DIM + c;
            else           src = ((size_t)(c >> 6) * E_DIM + e) * 64 + (c & 63);
            tile[ty + i * 8][tx] = f2b(in[src]);
        }
        __syncthreads();
#pragma unroll
        for (int i = 0; i < 4; ++i) {
            int c = bx * 32 + ty + i * 8;
            int e = by * 32 + tx;
            out[(size_t)c * E_DIM + e] = tile[tx][ty + i * 8];
        }
    } else if (blk < 15872) {    // mask -> additive-bias bf16, attn lane order
        // layout [b][kt:32][q0t:16][w:8][ld:2][lane:64][el:8]
        int g = (blk - 11776) * 256 + tid;            // 0..1048575
        int lane = g & 63, ld = (g >> 6) & 1, wv = (g >> 7) & 7;
        int q0t = (g >> 10) & 15, ktz = (g >> 14) & 31, bb = g >> 19;
        int quad = lane >> 4, l16 = lane & 15;
        int qq = q0t * 128 + wv * 16 + l16;
        int t0 = ktz * 64 + ld * 32 + quad * 4;
        const int* mp = mask + ((size_t)bb * S_LEN + qq) * S_LEN + t0;
        int4 ma = *(const int4*)mp;
        int4 mb2 = *(const int4*)(mp + 16);
        const us16 NEGB = f2b(-1e38f);
        us16 t8[8];
        t8[0] = ma.x ? NEGB : (us16)0;  t8[1] = ma.y ? NEGB : (us16)0;
        t8[2] = ma.z ? NEGB : (us16)0;  t8[3] = ma.w ? NEGB : (us16)0;
        t8[4] = mb2.x ? NEGB : (us16)0; t8[5] = mb2.y ? NEGB : (us16)0;
        t8[6] = mb2.z ? NEGB : (us16)0; t8[7] = mb2.w ? NEGB : (us16)0;
        *(uint4*)&marr[(size_t)g * 8] = *(const uint4*)t8;
    } else if (blk < 15920) {    // combined bias (Q-bias pre-scaled by SCALE2)
        int t = blk - 15872, z = t >> 4, h = t & 15;
        const float* bg = z == 0 ? bq : z == 1 ? bk : bv;
        const float* Wh = z == 0 ? Whq : z == 1 ? Whk : Whv;
        const float* bh = z == 0 ? bhq : z == 1 ? bhk : bhv;
        float* bc = z == 0 ? bcq : z == 1 ? bck : bcv;
        float sc = (z == 0) ? SCALE2 : 1.0f;
        int d = tid & 63, part = tid >> 6;
        float acc = 0.f;
        int j0 = part * 256;
        for (int j = j0; j < j0 + 256; ++j)
            acc += bg[j] * Wh[((size_t)h * E_DIM + j) * HD_DIM + d];
        red[part][d] = acc;
        __syncthreads();
        if (tid < 64)
            bc[h * 64 + tid] = (red[0][tid] + red[1][tid] + red[2][tid] + red[3][tid] + bh[h * 64 + tid]) * sc;
    } else {                     // zero zbias
        int i = (blk - 15920) * 256 + tid;
        if (i < 1024) zbias[i] = 0.f;
    }
}

// ---------------------------------------------------------------------------
// GEMM body, 128x128x32 tile (big batched projections).
// omode 1: bf16 [B,H,S,HD] (bias[col]); 3: bf16 [B,H,HD,S] (bias[row]).
// ---------------------------------------------------------------------------
#define BK 32

__device__ __forceinline__ void gemm_body(
    const us16* __restrict__ A, const us16* __restrict__ Bt,
    const float* __restrict__ bias, void* __restrict__ Cp,
    int M, int N, int K, int bxt, int byt, int omode)
{
    __shared__ us16 As[128 * BK];
    __shared__ us16 Bs[128 * BK];

    int tid = threadIdx.x;
    int wave = tid >> 6, lane = tid & 63;
    int quad = lane >> 4, l16 = lane & 15;
    int wm = (wave >> 1) * 64, wn = (wave & 1) * 64;
    int bm0 = byt * 128, bn0 = bxt * 128;
    int srow = lane >> 2;
    int gcol = (((lane & 3) ^ (srow & 3)) << 3);
    int rslot = ((quad ^ (l16 & 3)) << 3);

    float4v acc[4][4];
#pragma unroll
    for (int i = 0; i < 4; ++i)
#pragma unroll
        for (int j = 0; j < 4; ++j)
#pragma unroll
            for (int r = 0; r < 4; ++r) acc[i][j][r] = 0.f;

    for (int k0 = 0; k0 < K; k0 += BK) {
#pragma unroll
        for (int c = 0; c < 2; ++c) {
            int r0 = 32 * wave + 16 * c;
            gload16(A  + (size_t)(bm0 + r0 + srow) * K + k0 + gcol, &As[r0 * BK]);
            gload16(Bt + (size_t)(bn0 + r0 + srow) * K + k0 + gcol, &Bs[r0 * BK]);
        }
        __syncthreads();
        short8 af[4], bfr[4];
#pragma unroll
        for (int i = 0; i < 4; ++i)
            af[i] = *(const short8*)&As[(wm + i * 16 + l16) * BK + rslot];
#pragma unroll
        for (int j = 0; j < 4; ++j)
            bfr[j] = *(const short8*)&Bs[(wn + j * 16 + l16) * BK + rslot];
#pragma unroll
        for (int i = 0; i < 4; ++i)
#pragma unroll
            for (int j = 0; j < 4; ++j)
                acc[i][j] = __builtin_amdgcn_mfma_f32_16x16x32_bf16(af[i], bfr[j], acc[i][j], 0, 0, 0);
        __syncthreads();
    }

#pragma unroll
    for (int i = 0; i < 4; ++i) {
#pragma unroll
        for (int j = 0; j < 4; ++j) {
#pragma unroll
            for (int r = 0; r < 4; ++r) {
                int row = bm0 + wm + i * 16 + quad * 4 + r;
                int col = bn0 + wn + j * 16 + l16;
                float vv = acc[i][j][r] + ((omode == 3) ? bias[row] : bias[col]);
                if (omode == 1) {
                    int b = row >> 11, s = row & 2047, h = col >> 6, d = col & 63;
                    ((us16*)Cp)[(((size_t)(b * H_DIM + h) * S_LEN + s) * HD_DIM) + d] = f2b(vv);
                } else {  // 3: row=c (h*64+d), col=b*2048+s -> [B,H,HD,S]
                    int h = row >> 6, d = row & 63, b = col >> 11, sl = col & 2047;
                    ((us16*)Cp)[(((size_t)(b * H_DIM + h) * HD_DIM + d) * S_LEN) + sl] = f2b(vv);
                }
            }
        }
    }
}

// all three fused projections in ONE 768-block dispatch (3 blocks/CU)
__global__ __launch_bounds__(256) void proj_all(
    const us16* __restrict__ qb, const us16* __restrict__ kb, const us16* __restrict__ vb,
    const us16* __restrict__ WcqT, const us16* __restrict__ WckT, const us16* __restrict__ WcvT,
    const float* __restrict__ bcq, const float* __restrict__ bck, const float* __restrict__ bcv,
    us16* __restrict__ qhb, us16* __restrict__ khb, us16* __restrict__ vtb)
{
    int bx = blockIdx.x;
    int z = bx >> 8, t = bx & 255;
    if (z == 0)      gemm_body(qb, WcqT, bcq, qhb, M_ROWS, E_DIM, E_DIM, t & 7, t >> 3, 1);
    else if (z == 1) gemm_body(kb, WckT, bck, khb, M_ROWS, E_DIM, E_DIM, t & 7, t >> 3, 1);
    else             gemm_body(WcvT, vb, bcv, vtb, E_DIM, M_ROWS, E_DIM, t & 31, t >> 5, 3);
}

// ---------------------------------------------------------------------------
// 64x128-tile GEMM body. OMODE 0: bf16 [M,N]; 2: f32 [M,N]. bias[col], *oscale.
// ---------------------------------------------------------------------------
template<int OMODE>
__device__ __forceinline__ void gemm64_body(
    const us16* __restrict__ A, const us16* __restrict__ Bt,
    const float* __restrict__ bias, void* __restrict__ Cp,
    int M, int N, int K, int bxt, int byt, float oscale)
{
    __shared__ us16 As[64 * BK];
    __shared__ us16 Bs[128 * BK];

    int tid = threadIdx.x;
    int wave = tid >> 6, lane = tid & 63;
    int quad = lane >> 4, l16 = lane & 15;
    int wm = (wave >> 1) * 32, wn = (wave & 1) * 64;
    int bm0 = byt * 64, bn0 = bxt * 128;
    int srow = lane >> 2;
    int gcol = (((lane & 3) ^ (srow & 3)) << 3);
    int rslot = ((quad ^ (l16 & 3)) << 3);

    float4v acc[2][4];
#pragma unroll
    for (int i = 0; i < 2; ++i)
#pragma unroll
        for (int j = 0; j < 4; ++j)
#pragma unroll
            for (int r = 0; r < 4; ++r) acc[i][j][r] = 0.f;

    for (int k0 = 0; k0 < K; k0 += BK) {
        gload16(A + (size_t)(bm0 + 16 * wave + srow) * K + k0 + gcol, &As[16 * wave * BK]);
#pragma unroll
        for (int c = 0; c < 2; ++c) {
            int r0 = 32 * wave + 16 * c;
            gload16(Bt + (size_t)(bn0 + r0 + srow) * K + k0 + gcol, &Bs[r0 * BK]);
        }
        __syncthreads();
        short8 af[2], bfr[4];
#pragma unroll
        for (int i = 0; i < 2; ++i)
            af[i] = *(const short8*)&As[(wm + i * 16 + l16) * BK + rslot];
#pragma unroll
        for (int j = 0; j < 4; ++j)
            bfr[j] = *(const short8*)&Bs[(wn + j * 16 + l16) * BK + rslot];
#pragma unroll
        for (int i = 0; i < 2; ++i)
#pragma unroll
            for (int j = 0; j < 4; ++j)
                acc[i][j] = __builtin_amdgcn_mfma_f32_16x16x32_bf16(af[i], bfr[j], acc[i][j], 0, 0, 0);
        __syncthreads();
    }

#pragma unroll
    for (int i = 0; i < 2; ++i)
#pragma unroll
        for (int j = 0; j < 4; ++j)
#pragma unroll
            for (int r = 0; r < 4; ++r) {
                int row = bm0 + wm + i * 16 + quad * 4 + r;
                int col = bn0 + wn + j * 16 + l16;
                float vv = (acc[i][j][r] + bias[col]) * oscale;
                if (OMODE == 0) ((us16*)Cp)[(size_t)row * N + col] = f2b(vv);
                else            ((float*)Cp)[(size_t)row * N + col] = vv;
            }
}

// batched weight-combine: C_z = WhT_z @ Wb_z^T; z==0 output pre-scaled SCALE2
__global__ __launch_bounds__(256) void wgemm3(
    const us16* A0, const us16* A1, const us16* A2,
    const us16* B0, const us16* B1, const us16* B2,
    const float* zbias, us16* C0, us16* C1, us16* C2)
{
    int z = blockIdx.z;
    const us16* A = z == 0 ? A0 : z == 1 ? A1 : A2;
    const us16* Bt = z == 0 ? B0 : z == 1 ? B1 : B2;
    us16* C = z == 0 ? C0 : z == 1 ? C1 : C2;
    float sc = (z == 0) ? SCALE2 : 1.0f;
    gemm64_body<0>(A, Bt, zbias, C, E_DIM, E_DIM, E_DIM, blockIdx.x, blockIdx.y, sc);
}

// out projection: f32 out, grid (8,64)=512 blocks
__global__ __launch_bounds__(256) void gemm_out64(
    const us16* __restrict__ A, const us16* __restrict__ Bt,
    const float* __restrict__ bias, float* __restrict__ C, int M, int N, int K)
{
    gemm64_body<2>(A, Bt, bias, C, M, N, K, blockIdx.x, blockIdx.y, 1.0f);
}

// ---------------------------------------------------------------------------
// Flash attention, S^T formulation (fixed-max softmax; scores pre-scaled via
// Wcq). Mask = bf16 additive bias (marr) as MFMA C-init; P via cvt_pk; l via
// ones-MFMA. Depth-2 pipeline with COUNTED vmcnt (T3/T4): per tile
//   SM(t) -> PV(t) -> barrier -> issue DMA(t+2) -> vmcnt(2) -> barrier
//   -> QK(t+1)
// FULL-S per block (no K-split): block = (bh, q0t), NT=32 K-tiles; O is
// finalized in-kernel (divide by l) and written straight to x -- no partials,
// no combine dispatch. Grid 512 blocks = exactly 2/CU, all co-resident
// (LDS 50 KB allows 3/CU) -> zero dispatch tail.
// XCD-aware 1-D grid (4 heads/XCD). 512 thr = 8 waves, Q-tile 128.
// ---------------------------------------------------------------------------
#define PST 72   // Pw row stride (els)
#define NT 32    // K-tiles per block (64 wide, full S)

__global__ __launch_bounds__(512) void attn_kernel(
    const us16* __restrict__ qh, const us16* __restrict__ kh,
    const us16* __restrict__ vt, const us16* __restrict__ marr,
    us16* __restrict__ x)
{
    __shared__ us16 Ks[2][64 * 64];   // packed, swizzled: slot c holds chunk c^(t&7)
    __shared__ us16 Vs[2][64 * 64];
    __shared__ us16 Pw[8][16 * PST];

    int tid = threadIdx.x;
    int w = tid >> 6, lane = tid & 63;
    int quad = lane >> 4, l16 = lane & 15;

    // XCD-aware decode: 4 heads per XCD so K/V panels stay L2-resident.
    int wg = blockIdx.x;                 // 0..511
    int xcd = wg & 7, idx = wg >> 3;     // 64 blocks per XCD
    int bh = xcd * 4 + (idx >> 4);       // 4 bh per XCD
    int q0t = idx & 15;
    int q0 = q0t * 128;
    int b = bh >> 4;
    const size_t base = (size_t)bh * (S_LEN * HD_DIM);

    int qrow = q0 + w * 16 + l16;
    short8 qf0, qf1;
    {
        const us16* qp = qh + base + (size_t)qrow * HD_DIM + quad * 8;
        qf0 = *(const short8*)qp;
        qf1 = *(const short8*)(qp + 32);
    }

    // ones B-fragment for l = P x 1 (all bf16 1.0)
    short8 onesf;
#pragma unroll
    for (int j = 0; j < 8; ++j) onesf[j] = (short)0x3F80;

    // staging geometry: wave w stages rows w*8..w*8+7; slot c <- chunk c^(row&7)
    int strow = w * 8 + (lane >> 3);
    int scol = ((lane & 7) ^ (strow & 7)) * 8;
    const us16* ksrc0 = kh + base + (size_t)strow * HD_DIM + scol;
    const us16* vsrc0 = vt + base + (size_t)strow * S_LEN + scol;

    // mask-bias base: [b][kt:32][q0t:16][w:8][ld:2][lane:64][el:8]
    const us16* mb0p = marr + ((((size_t)(b * 32) * 16 + q0t) * 8 + w) * 1024)
                            + (size_t)lane * 8;

    // frag-read slots
    int slotA = (quad ^ (l16 & 7)) * 8;     // chunk quad
    int slotB = slotA ^ 32;                 // chunk quad+4

    float4v o[4];
#pragma unroll
    for (int dt = 0; dt < 4; ++dt)
#pragma unroll
        for (int r = 0; r < 4; ++r) o[dt][r] = 0.f;
    float4v o_l;
#pragma unroll
    for (int r = 0; r < 4; ++r) o_l[r] = 0.f;

    // QK for tile in KsC with mask C-init (m0,m1) -> sc[4]
    auto QK = [&](const us16* KsC, uint4 m0, uint4 m1, float4v* sc) {
        __builtin_amdgcn_s_setprio(1);
#pragma unroll
        for (int ct = 0; ct < 4; ++ct) {
            int tt = ct * 16 + l16;
            short8 kf0 = *(const short8*)&KsC[tt * 64 + slotA];
            short8 kf1 = *(const short8*)&KsC[tt * 64 + slotB];
            unsigned w0, w1;
            if (ct == 0)      { w0 = m0.x; w1 = m0.y; }
            else if (ct == 1) { w0 = m0.z; w1 = m0.w; }
            else if (ct == 2) { w0 = m1.x; w1 = m1.y; }
            else              { w0 = m1.z; w1 = m1.w; }
            float4v a;
            a[0] = __uint_as_float(w0 << 16);
            a[1] = __uint_as_float(w0 & 0xFFFF0000u);
            a[2] = __uint_as_float(w1 << 16);
            a[3] = __uint_as_float(w1 & 0xFFFF0000u);
            a = __builtin_amdgcn_mfma_f32_16x16x32_bf16(kf0, qf0, a, 0, 0, 0);
            a = __builtin_amdgcn_mfma_f32_16x16x32_bf16(kf1, qf1, a, 0, 0, 0);
            sc[ct] = a;
        }
        __builtin_amdgcn_s_setprio(0);
    };

    // prologue: stage tiles 0 and 1; mask(0); wait tile 0 only; QK(0)
    gload16(ksrc0, &Ks[0][w * 512]);
    gload16(vsrc0, &Vs[0][w * 512]);
    gload16(ksrc0 + (size_t)64 * HD_DIM, &Ks[1][w * 512]);
    gload16(vsrc0 + 64, &Vs[1][w * 512]);
    uint4 mc0 = *(const uint4*)(mb0p);
    uint4 mc1 = *(const uint4*)(mb0p + 512);
    asm volatile("s_waitcnt vmcnt(2)" ::: "memory");
    __builtin_amdgcn_s_barrier();
    __builtin_amdgcn_sched_barrier(0);

    float4v sc[4];
    QK(Ks[0], mc0, mc1, sc);

    for (int t = 0; t < NT; ++t) {
        int cur = t & 1;

        // mask(t+1) load early (hides under SM+PV)
        uint4 mn0 = mc0, mn1 = mc1;
        if (t + 1 < NT) {
            const us16* mp = mb0p + (size_t)(t + 1) * 131072;
            mn0 = *(const uint4*)(mp);
            mn1 = *(const uint4*)(mp + 512);
        }

        // SM(t): exp2 + cvt_pk pack + b64 write (scores pre-scaled via Wcq)
#pragma unroll
        for (int ct = 0; ct < 4; ++ct) {
            float p0 = __builtin_amdgcn_exp2f(sc[ct][0]);
            float p1 = __builtin_amdgcn_exp2f(sc[ct][1]);
            float p2 = __builtin_amdgcn_exp2f(sc[ct][2]);
            float p3 = __builtin_amdgcn_exp2f(sc[ct][3]);
            uint2 pk;
            asm("v_cvt_pk_bf16_f32 %0, %1, %2" : "=v"(pk.x) : "v"(p0), "v"(p1));
            asm("v_cvt_pk_bf16_f32 %0, %1, %2" : "=v"(pk.y) : "v"(p2), "v"(p3));
            *(uint2*)&Pw[w][l16 * PST + ct * 16 + quad * 4] = pk;
        }

        // PV(t): O += P.V ; l += P.1 (ones-MFMA)
        short8 pf0 = *(const short8*)&Pw[w][l16 * PST + quad * 8];
        short8 pf1 = *(const short8*)&Pw[w][l16 * PST + 32 + quad * 8];
        const us16* VsC = Vs[cur];
        __builtin_amdgcn_s_setprio(1);
#pragma unroll
        for (int dt = 0; dt < 4; ++dt) {
            int d = dt * 16 + l16;
            short8 vf0 = *(const short8*)&VsC[d * 64 + slotA];
            short8 vf1 = *(const short8*)&VsC[d * 64 + slotB];
            o[dt] = __builtin_amdgcn_mfma_f32_16x16x32_bf16(pf0, vf0, o[dt], 0, 0, 0);
            o[dt] = __builtin_amdgcn_mfma_f32_16x16x32_bf16(pf1, vf1, o[dt], 0, 0, 0);
        }
        o_l = __builtin_amdgcn_mfma_f32_16x16x32_bf16(pf0, onesf, o_l, 0, 0, 0);
        o_l = __builtin_amdgcn_mfma_f32_16x16x32_bf16(pf1, onesf, o_l, 0, 0, 0);
        __builtin_amdgcn_s_setprio(0);

        if (t + 1 == NT) break;

        // all waves done reading buf[cur] -> safe to overwrite
        __builtin_amdgcn_s_barrier();
        __builtin_amdgcn_sched_barrier(0);

        if (t + 2 < NT) {
            gload16(ksrc0 + (size_t)((t + 2) * 64) * HD_DIM, &Ks[cur][w * 512]);
            gload16(vsrc0 + (t + 2) * 64, &Vs[cur][w * 512]);
            // outstanding: DMA(t+1)=2 + DMA(t+2)=2; wait until only t+2 remains
            asm volatile("s_waitcnt vmcnt(2)" ::: "memory");
        } else {
            // nothing more to issue; drain DMA(t+1)
            asm volatile("s_waitcnt vmcnt(0)" ::: "memory");
        }
        __builtin_amdgcn_s_barrier();
        __builtin_amdgcn_sched_barrier(0);

        // QK(t+1) from the freshly-ready buffer
        mc0 = mn0; mc1 = mn1;
        QK(Ks[cur ^ 1], mc0, mc1, sc);
    }

    // finalize: divide by l (o_l[r] = row-sum, equal across l16) and write x
    float linv[4];
#pragma unroll
    for (int r = 0; r < 4; ++r) linv[r] = 1.0f / o_l[r];
    int h = bh & 15;
    int srow0 = q0 + w * 16 + quad * 4;
#pragma unroll
    for (int r = 0; r < 4; ++r) {
        size_t xro = ((size_t)(b * S_LEN + srow0 + r)) * E_DIM + h * HD_DIM;
#pragma unroll
        for (int dt = 0; dt < 4; ++dt)
            x[xro + dt * 16 + l16] = f2b(o[dt][r] * linv[r]);
    }
}

// ---------------------------------------------------------------------------
extern "C" void kernel_launch(void* const* d_in, const int* in_sizes, int n_in,
                              void* d_out, int out_size, void* d_ws, size_t ws_size,
                              hipStream_t stream) {
    const float* q    = (const float*)d_in[0];
    const float* k    = (const float*)d_in[1];
    const float* v    = (const float*)d_in[2];
    const int*   mask = (const int*)d_in[3];
    const float* Wq = (const float*)d_in[4];   const float* bq = (const float*)d_in[5];
    const float* Wk = (const float*)d_in[6];   const float* bk = (const float*)d_in[7];
    const float* Wv = (const float*)d_in[8];   const float* bv = (const float*)d_in[9];
    const float* Whq = (const float*)d_in[10]; const float* bhq = (const float*)d_in[11];
    const float* Whk = (const float*)d_in[12]; const float* bhk = (const float*)d_in[13];
    const float* Whv = (const float*)d_in[14]; const float* bhv = (const float*)d_in[15];
    const float* Wo = (const float*)d_in[16];  const float* bo = (const float*)d_in[17];

    us16* ws = (us16*)d_ws;
    const size_t M1 = (size_t)1 << 20;  // 1M bf16 elems = 2 MiB
    us16* WhqT = ws + 0 * M1;
    us16* WhkT = ws + 1 * M1;
    us16* WhvT = ws + 2 * M1;
    us16* WoT  = ws + 3 * M1;
    us16* WcqT = ws + 4 * M1;
    us16* WckT = ws + 5 * M1;
    us16* WcvT = ws + 6 * M1;
    us16* Wqb  = ws + 7 * M1;
    us16* Wkb  = ws + 8 * M1;
    us16* Wvb  = ws + 9 * M1;
    us16* qb   = ws + 10 * M1;   // 4M els each
    us16* kb   = ws + 14 * M1;
    us16* vb   = ws + 18 * M1;
    us16* qhb  = ws + 22 * M1;   // [B,H,S,HD]
    us16* khb  = ws + 26 * M1;
    us16* vtb  = ws + 30 * M1;   // [B,H,HD,S]
    us16* xb   = vb;             // vb dead after proj_all
    float* bcq   = (float*)(ws + 34 * M1);
    float* bck   = bcq + 1024;
    float* bcv   = bck + 1024;
    float* zbias = bcv + 1024;
    us16*  marr  = ws + 35 * M1;                         // 8M els = 16 MiB

    prep<<<15924, 256, 0, stream>>>(q, k, v, Wq, Wk, Wv, Whq, Whk, Whv, Wo,
                                    bq, bk, bv, bhq, bhk, bhv, mask,
                                    qb, kb, vb, Wqb, Wkb, Wvb,
                                    WhqT, WhkT, WhvT, WoT, marr,
                                    bcq, bck, bcv, zbias);

    // combined weights WcT[c][e] = sum_j Wh[h][j][d]*W[e][j] (Q pre-scaled)
    wgemm3<<<dim3(8, 16, 3), 256, 0, stream>>>(WhqT, WhkT, WhvT, Wqb, Wkb, Wvb, zbias,
                                               WcqT, WckT, WcvT);

    // all three projections in one 768-block dispatch
    proj_all<<<768, 256, 0, stream>>>(qb, kb, vb, WcqT, WckT, WcvT,
                                      bcq, bck, bcv, qhb, khb, vtb);

    // full-S flash attention, finalizes x in-kernel (no combine dispatch)
    attn_kernel<<<512, 512, 0, stream>>>(qhb, khb, vtb, marr, xb);

    // output projection, f32 out
    gemm_out64<<<dim3(8, 64), 256, 0, stream>>>(xb, WoT, bo, (float*)d_out,
                                                M_ROWS, E_DIM, E_DIM);
}